// Round 1
// baseline (364.244 us; speedup 1.0000x reference)
//
#include <hip/hip_runtime.h>
#include <math.h>

// Problem constants (b=16, n=512, h=1024)
#define NB 16
#define SEQ 512
#define HID 1024
#define XDIM 128       // 2*HEAD_SIZE
#define NHEADS 12
#define NROWS (NB*SEQ) // 8192
#define NEG_BIG 1000000000000.0f

// ---------------------------------------------------------------------------
// Stage 1: x = inp@W1 + b1 ; RoPE(even/odd split) -> qw', kw' ; bias = (x@W2+b2)/2
// Grid: 256 blocks x 256 threads, 32 rows/block.
// ---------------------------------------------------------------------------
__global__ __launch_bounds__(256) void egp_stage1(
    const float* __restrict__ inp,   // (8192, 1024)
    const float* __restrict__ W1,    // (1024, 128)
    const float* __restrict__ b1,    // (128)
    const float* __restrict__ W2,    // (128, 24)
    const float* __restrict__ b2,    // (24)
    float* __restrict__ qw,          // (8192, 64)
    float* __restrict__ kw,          // (8192, 64)
    float* __restrict__ biasw)       // (8192, 24)  (already /2)
{
    __shared__ float As[32][33];        // pad +1: breaks row-stride bank alias
    __shared__ float Bs[32][128];
    __shared__ float Xs[32][132];       // x rows for the bias GEMM
    __shared__ float W2s[128*24];
    __shared__ float b2s[24];

    const int t    = threadIdx.x;
    const int row0 = blockIdx.x * 32;
    const int tx   = t & 15;   // col group: cols tx*8 .. tx*8+7
    const int ty   = t >> 4;   // rows ty*2, ty*2+1

    for (int i = t; i < 128*24; i += 256) W2s[i] = W2[i];
    if (t < 24) b2s[t] = b2[t];

    float b1v[8];
    #pragma unroll
    for (int j = 0; j < 8; j++) b1v[j] = b1[tx*8 + j];

    float acc[2][8];
    #pragma unroll
    for (int i = 0; i < 2; i++)
        #pragma unroll
        for (int j = 0; j < 8; j++) acc[i][j] = 0.0f;

    const int lr = t >> 3;          // A-tile row this thread loads
    const int lc = (t & 7) * 4;     // A-tile col (float4)

    for (int k0 = 0; k0 < HID; k0 += 32) {
        float4 a4 = *(const float4*)(inp + (size_t)(row0 + lr)*HID + k0 + lc);
        #pragma unroll
        for (int j = 0; j < 4; j++) {
            int f4 = t + 256*j;            // 1024 float4 total
            int r  = f4 >> 5;              // 32 float4 per 128-col row
            int c  = (f4 & 31) << 2;
            *(float4*)(&Bs[r][c]) = *(const float4*)(W1 + (size_t)(k0 + r)*XDIM + c);
        }
        As[lr][lc+0] = a4.x; As[lr][lc+1] = a4.y;
        As[lr][lc+2] = a4.z; As[lr][lc+3] = a4.w;
        __syncthreads();
        #pragma unroll
        for (int k = 0; k < 32; k++) {
            float a0 = As[ty*2  ][k];
            float a1 = As[ty*2+1][k];
            float4 bA = *(const float4*)(&Bs[k][tx*8]);
            float4 bB = *(const float4*)(&Bs[k][tx*8+4]);
            acc[0][0] += a0*bA.x; acc[0][1] += a0*bA.y; acc[0][2] += a0*bA.z; acc[0][3] += a0*bA.w;
            acc[0][4] += a0*bB.x; acc[0][5] += a0*bB.y; acc[0][6] += a0*bB.z; acc[0][7] += a0*bB.w;
            acc[1][0] += a1*bA.x; acc[1][1] += a1*bA.y; acc[1][2] += a1*bA.z; acc[1][3] += a1*bA.w;
            acc[1][4] += a1*bB.x; acc[1][5] += a1*bB.y; acc[1][6] += a1*bB.z; acc[1][7] += a1*bB.w;
        }
        __syncthreads();
    }

    // RoPE epilogue. Thread owns x cols [8tx, 8tx+8).
    // Layout of 4 consecutive x cols at 4i: [q[2i], k[2i], q[2i+1], k[2i+1]].
    // This thread covers pair indices i0=2tx (cols 8tx..) and i1=2tx+1 (cols 8tx+4..).
    const float LOG1E4 = 9.210340371976184f;  // ln(10000)
    float inv0 = expf(-((float)(2*tx  ) * (1.0f/32.0f)) * LOG1E4);
    float inv1 = expf(-((float)(2*tx+1) * (1.0f/32.0f)) * LOG1E4);

    #pragma unroll
    for (int i = 0; i < 2; i++) {
        int r    = ty*2 + i;
        int grow = row0 + r;
        float pos = (float)(grow & (SEQ-1));
        float x[8];
        #pragma unroll
        for (int j = 0; j < 8; j++) { x[j] = acc[i][j] + b1v[j]; Xs[r][tx*8+j] = x[j]; }
        float s0 = sinf(pos*inv0), c0 = cosf(pos*inv0);
        float s1 = sinf(pos*inv1), c1 = cosf(pos*inv1);
        float4 q4, k4;
        q4.x = x[0]*c0 - x[2]*s0;   // q'[2i0]
        q4.y = x[2]*c0 + x[0]*s0;   // q'[2i0+1]
        q4.z = x[4]*c1 - x[6]*s1;   // q'[2i1]
        q4.w = x[6]*c1 + x[4]*s1;   // q'[2i1+1]
        k4.x = x[1]*c0 - x[3]*s0;
        k4.y = x[3]*c0 + x[1]*s0;
        k4.z = x[5]*c1 - x[7]*s1;
        k4.w = x[7]*c1 + x[5]*s1;
        *(float4*)(qw + (size_t)grow*64 + tx*4) = q4;   // d = 4tx..4tx+3
        *(float4*)(kw + (size_t)grow*64 + tx*4) = k4;
    }
    __syncthreads();

    // bias GEMM: 32 rows x 24 cols = 768 outputs, 3 per thread
    #pragma unroll
    for (int u = 0; u < 3; u++) {
        int o   = t + 256*u;
        int row = o / 24;
        int jj  = o - row*24;
        float s = 0.0f;
        for (int kk = 0; kk < 128; kk++)
            s += Xs[row][kk] * W2s[kk*24 + jj];
        biasw[(size_t)(row0 + row)*24 + jj] = (s + b2s[jj]) * 0.5f;
    }
}

// ---------------------------------------------------------------------------
// Stage 2: qk[m,n] = (q'[m]·k'[n])/8 computed ONCE per (b,m,n) tile, then
// broadcast over 12 heads: out = qk + biasE[2h][n] + biasO[2h+1][m] - masks.
// Grid: (8 n-tiles, 8 m-tiles, 16 batches), 64x64 tile, 256 threads, 4x4/thread.
// ---------------------------------------------------------------------------
__global__ __launch_bounds__(256) void egp_stage2(
    const float* __restrict__ qw,
    const float* __restrict__ kw,
    const float* __restrict__ biasw,
    const float* __restrict__ am,    // (16, 512)
    float* __restrict__ out)         // (16, 12, 512, 512)
{
    __shared__ float Qs[64][68];     // pad +4 keeps float4 alignment, breaks bank alias
    __shared__ float Ks[64][68];
    __shared__ float bEs[12][64];
    __shared__ float bOs[12][64];
    __shared__ float amN[64];
    __shared__ float amM[64];

    const int b  = blockIdx.z;
    const int m0 = blockIdx.y * 64;
    const int n0 = blockIdx.x * 64;
    const int t  = threadIdx.x;
    const int tx = t & 15;   // n dir: cols tx*4..+3
    const int ty = t >> 4;   // m dir: rows ty*4..+3

    #pragma unroll
    for (int j = 0; j < 4; j++) {
        int f4 = t + 256*j;           // 1024 float4 per tile
        int r  = f4 >> 4;             // 16 float4 per 64-col row
        int c  = (f4 & 15) << 2;
        *(float4*)(&Qs[r][c]) = *(const float4*)(qw + (size_t)(b*SEQ + m0 + r)*64 + c);
        *(float4*)(&Ks[r][c]) = *(const float4*)(kw + (size_t)(b*SEQ + n0 + r)*64 + c);
    }
    for (int o = t; o < 768; o += 256) {
        int nn = o & 63;
        int h  = o >> 6;
        bEs[h][nn] = biasw[(size_t)(b*SEQ + n0 + nn)*24 + 2*h];
        bOs[h][nn] = biasw[(size_t)(b*SEQ + m0 + nn)*24 + 2*h + 1];
    }
    if (t < 64)       amN[t]      = am[b*SEQ + n0 + t];
    else if (t < 128) amM[t - 64] = am[b*SEQ + m0 + (t - 64)];
    __syncthreads();

    float acc[4][4];
    #pragma unroll
    for (int i = 0; i < 4; i++)
        #pragma unroll
        for (int j = 0; j < 4; j++) acc[i][j] = 0.0f;

    for (int k = 0; k < 64; k += 4) {
        float4 qv[4], kv[4];
        #pragma unroll
        for (int i = 0; i < 4; i++) qv[i] = *(const float4*)(&Qs[ty*4+i][k]);
        #pragma unroll
        for (int j = 0; j < 4; j++) kv[j] = *(const float4*)(&Ks[tx*4+j][k]);
        #pragma unroll
        for (int i = 0; i < 4; i++)
            #pragma unroll
            for (int j = 0; j < 4; j++)
                acc[i][j] += qv[i].x*kv[j].x + qv[i].y*kv[j].y
                           + qv[i].z*kv[j].z + qv[i].w*kv[j].w;
    }

    float amMv[4], amNv[4];
    #pragma unroll
    for (int i = 0; i < 4; i++) amMv[i] = amM[ty*4 + i];
    #pragma unroll
    for (int j = 0; j < 4; j++) amNv[j] = amN[tx*4 + j];

    // fold scale (1/8) and both masks once; head loop only adds biases
    float vals[4][4];
    #pragma unroll
    for (int i = 0; i < 4; i++) {
        int m = m0 + ty*4 + i;
        #pragma unroll
        for (int j = 0; j < 4; j++) {
            int n = n0 + tx*4 + j;
            float msk = (1.0f - amMv[i]*amNv[j]) * NEG_BIG
                      + ((n < m) ? NEG_BIG : 0.0f);
            vals[i][j] = acc[i][j] * 0.125f - msk;
        }
    }

    for (int h = 0; h < NHEADS; h++) {
        float be[4], bo[4];
        #pragma unroll
        for (int j = 0; j < 4; j++) be[j] = bEs[h][tx*4 + j];
        #pragma unroll
        for (int i = 0; i < 4; i++) bo[i] = bOs[h][ty*4 + i];
        float* obase = out + ((size_t)((b*NHEADS + h)*SEQ + m0 + ty*4))*SEQ + n0 + tx*4;
        #pragma unroll
        for (int i = 0; i < 4; i++) {
            float4 o4;
            o4.x = vals[i][0] + be[0] + bo[i];
            o4.y = vals[i][1] + be[1] + bo[i];
            o4.z = vals[i][2] + be[2] + bo[i];
            o4.w = vals[i][3] + be[3] + bo[i];
            *(float4*)(obase + (size_t)i*SEQ) = o4;
        }
    }
}

extern "C" void kernel_launch(void* const* d_in, const int* in_sizes, int n_in,
                              void* d_out, int out_size, void* d_ws, size_t ws_size,
                              hipStream_t stream) {
    const float* inp = (const float*)d_in[0];   // (16,512,1024)
    const float* am  = (const float*)d_in[1];   // (16,512)
    const float* W1  = (const float*)d_in[2];   // (1024,128)
    const float* b1  = (const float*)d_in[3];   // (128)
    const float* W2  = (const float*)d_in[4];   // (128,24)
    const float* b2  = (const float*)d_in[5];   // (24)
    float* out = (float*)d_out;

    // workspace layout: qw (2MB) | kw (2MB) | bias (768KB) — ~4.75MB total
    float* qw   = (float*)d_ws;
    float* kw   = qw + (size_t)NROWS*64;
    float* bias = kw + (size_t)NROWS*64;

    egp_stage1<<<NROWS/32, 256, 0, stream>>>(inp, W1, b1, W2, b2, qw, kw, bias);

    dim3 g2(SEQ/64, SEQ/64, NB);
    egp_stage2<<<g2, 256, 0, stream>>>(qw, kw, bias, am, out);
}

// Round 2
// 263.763 us; speedup vs baseline: 1.3810x; 1.3810x over previous
//
#include <hip/hip_runtime.h>
#include <math.h>

// Problem constants (b=16, n=512, h=1024)
#define NB 16
#define SEQ 512
#define HID 1024
#define XDIM 128       // 2*HEAD_SIZE
#define NHEADS 12
#define NROWS (NB*SEQ) // 8192
#define NEG_BIG 1000000000000.0f
#define MTILE 16

typedef __bf16 bf16x8 __attribute__((ext_vector_type(8)));
typedef __bf16 bf16x4 __attribute__((ext_vector_type(4)));
typedef float  f32x4  __attribute__((ext_vector_type(4)));

// ---------------------------------------------------------------------------
// Prep: W1T[n][k] = bf16(W1[k][n])  (128 x 1024 bf16, B^T layout for MFMA)
// ---------------------------------------------------------------------------
__global__ __launch_bounds__(256) void egp_prep(
    const float* __restrict__ W1, __bf16* __restrict__ W1T)
{
    int idx = blockIdx.x * 256 + threadIdx.x;   // 16384 threads
    int n   = idx >> 7;                         // 0..127
    int k0  = (idx & 127) << 3;                 // 0..1016 step 8
    bf16x8 o;
    #pragma unroll
    for (int j = 0; j < 8; j++)
        o[j] = (__bf16)W1[(size_t)(k0 + j) * XDIM + n];
    *(bf16x8*)(W1T + (size_t)n * HID + k0) = o;
}

// ---------------------------------------------------------------------------
// Stage 1 (MFMA): x = inp@W1 + b1 ; RoPE -> qw', kw' ; bias = (x@W2+b2)/2
// Grid: 512 blocks x 256 threads (4 waves), 16 rows/block.
// A staged fp32->bf16 into LDS in a-frag layout (lane-linear, conflict-free);
// B-frags read directly from W1T in global (L2-resident, 256 KB).
// ---------------------------------------------------------------------------
__global__ __launch_bounds__(256) void egp_stage1(
    const float* __restrict__ inp,   // (8192, 1024) fp32
    const __bf16* __restrict__ W1T,  // (128, 1024) bf16
    const float* __restrict__ b1,    // (128)
    const float* __restrict__ W2,    // (128, 24)
    const float* __restrict__ b2,    // (24)
    float* __restrict__ qw,          // (8192, 64)
    float* __restrict__ kw,          // (8192, 64)
    float* __restrict__ biasw)       // (8192, 24)  (already /2)
{
    // As: one 64-k chunk of the 16-row A tile, bf16, stored in MFMA a-frag
    // order: elem (m, k) -> [kstep s=k>>5][quad=(k&31)>>3][m][j=k&7]
    __shared__ __bf16 As[2048];          // 4 KB
    __shared__ float  Xs[MTILE][132];    // x rows for RoPE + bias GEMM (pad)
    __shared__ float  W2s[XDIM * 24];    // 12 KB
    __shared__ float  b2s[24];

    const int t    = threadIdx.x;
    const int row0 = blockIdx.x * MTILE;
    const int lane = t & 63;
    const int w    = t >> 6;        // wave 0..3 -> cols [32w, 32w+32)
    const int quad = lane >> 4;
    const int mrow = lane & 15;
    const int ncol0 = w * 32;

    for (int i = t; i < XDIM * 24; i += 256) W2s[i] = W2[i];
    if (t < 24) b2s[t] = b2[t];

    // staging assignment: thread t handles row m_st, k-chunk offsets k_st..k_st+3
    const int m_st = t >> 4;
    const int k_st = (t & 15) * 4;
    const int s_st  = k_st >> 5;
    const int q_st  = (k_st & 31) >> 3;
    const int j_st  = k_st & 7;          // 0 or 4
    const int off_st = s_st * 1024 + q_st * 128 + m_st * 8 + j_st;
    const float* aptr = inp + (size_t)(row0 + m_st) * HID + k_st;

    f32x4 acc0 = {0.f, 0.f, 0.f, 0.f};
    f32x4 acc1 = {0.f, 0.f, 0.f, 0.f};

    float4 v = *(const float4*)(aptr);

    for (int kc = 0; kc < HID; kc += 64) {
        __syncthreads();   // previous chunk's compute done before overwrite
        bf16x4 p;
        p[0] = (__bf16)v.x; p[1] = (__bf16)v.y;
        p[2] = (__bf16)v.z; p[3] = (__bf16)v.w;
        *(bf16x4*)(&As[off_st]) = p;
        __syncthreads();
        if (kc + 64 < HID) v = *(const float4*)(aptr + kc + 64);  // prefetch

        #pragma unroll
        for (int s2 = 0; s2 < 2; s2++) {
            bf16x8 a = *(bf16x8*)(&As[s2 * 1024 + quad * 128 + mrow * 8]);
            {
                const __bf16* bp = W1T + (size_t)(ncol0 + mrow) * HID
                                 + kc + s2 * 32 + quad * 8;
                bf16x8 b = *(const bf16x8*)(bp);
                acc0 = __builtin_amdgcn_mfma_f32_16x16x32_bf16(a, b, acc0, 0, 0, 0);
            }
            {
                const __bf16* bp = W1T + (size_t)(ncol0 + 16 + mrow) * HID
                                 + kc + s2 * 32 + quad * 8;
                bf16x8 b = *(const bf16x8*)(bp);
                acc1 = __builtin_amdgcn_mfma_f32_16x16x32_bf16(a, b, acc1, 0, 0, 0);
            }
        }
    }

    // epilogue: C/D layout col=lane&15, row=quad*4+reg  (m89/m91-verified)
    float b1v0 = b1[ncol0 + mrow];
    float b1v1 = b1[ncol0 + 16 + mrow];
    #pragma unroll
    for (int r = 0; r < 4; r++) {
        Xs[quad * 4 + r][ncol0 + mrow]      = acc0[r] + b1v0;
        Xs[quad * 4 + r][ncol0 + 16 + mrow] = acc1[r] + b1v1;
    }
    __syncthreads();

    // RoPE (round-0-verified math). Thread owns x cols [8tx, 8tx+8) of row r.
    const int tx = t & 15;
    const int r  = t >> 4;
    const float LOG1E4 = 9.210340371976184f;  // ln(10000)
    float inv0 = expf(-((float)(2 * tx)     * (1.0f / 32.0f)) * LOG1E4);
    float inv1 = expf(-((float)(2 * tx + 1) * (1.0f / 32.0f)) * LOG1E4);
    {
        int grow  = row0 + r;
        float pos = (float)(grow & (SEQ - 1));
        float x[8];
        #pragma unroll
        for (int j = 0; j < 8; j++) x[j] = Xs[r][tx * 8 + j];
        float s0 = sinf(pos * inv0), c0 = cosf(pos * inv0);
        float s1 = sinf(pos * inv1), c1 = cosf(pos * inv1);
        float4 q4, k4;
        q4.x = x[0] * c0 - x[2] * s0;
        q4.y = x[2] * c0 + x[0] * s0;
        q4.z = x[4] * c1 - x[6] * s1;
        q4.w = x[6] * c1 + x[4] * s1;
        k4.x = x[1] * c0 - x[3] * s0;
        k4.y = x[3] * c0 + x[1] * s0;
        k4.z = x[5] * c1 - x[7] * s1;
        k4.w = x[7] * c1 + x[5] * s1;
        *(float4*)(qw + (size_t)grow * 64 + tx * 4) = q4;
        *(float4*)(kw + (size_t)grow * 64 + tx * 4) = k4;
    }

    // bias GEMM: 16 rows x 24 cols = 384 outputs
    for (int o = t; o < MTILE * 24; o += 256) {
        int row = o / 24;
        int jj  = o - row * 24;
        float s = 0.0f;
        for (int kk = 0; kk < XDIM; kk++)
            s += Xs[row][kk] * W2s[kk * 24 + jj];
        biasw[(size_t)(row0 + row) * 24 + jj] = (s + b2s[jj]) * 0.5f;
    }
}

// ---------------------------------------------------------------------------
// Stage 2 (unchanged from R1): qk computed once per (b,m,n) tile, broadcast
// over 12 heads with per-head biases; masks folded once.
// ---------------------------------------------------------------------------
__global__ __launch_bounds__(256) void egp_stage2(
    const float* __restrict__ qw,
    const float* __restrict__ kw,
    const float* __restrict__ biasw,
    const float* __restrict__ am,    // (16, 512)
    float* __restrict__ out)         // (16, 12, 512, 512)
{
    __shared__ float Qs[64][68];
    __shared__ float Ks[64][68];
    __shared__ float bEs[12][64];
    __shared__ float bOs[12][64];
    __shared__ float amN[64];
    __shared__ float amM[64];

    const int b  = blockIdx.z;
    const int m0 = blockIdx.y * 64;
    const int n0 = blockIdx.x * 64;
    const int t  = threadIdx.x;
    const int tx = t & 15;
    const int ty = t >> 4;

    #pragma unroll
    for (int j = 0; j < 4; j++) {
        int f4 = t + 256 * j;
        int r  = f4 >> 4;
        int c  = (f4 & 15) << 2;
        *(float4*)(&Qs[r][c]) = *(const float4*)(qw + (size_t)(b * SEQ + m0 + r) * 64 + c);
        *(float4*)(&Ks[r][c]) = *(const float4*)(kw + (size_t)(b * SEQ + n0 + r) * 64 + c);
    }
    for (int o = t; o < 768; o += 256) {
        int nn = o & 63;
        int h  = o >> 6;
        bEs[h][nn] = biasw[(size_t)(b * SEQ + n0 + nn) * 24 + 2 * h];
        bOs[h][nn] = biasw[(size_t)(b * SEQ + m0 + nn) * 24 + 2 * h + 1];
    }
    if (t < 64)       amN[t]      = am[b * SEQ + n0 + t];
    else if (t < 128) amM[t - 64] = am[b * SEQ + m0 + (t - 64)];
    __syncthreads();

    float acc[4][4];
    #pragma unroll
    for (int i = 0; i < 4; i++)
        #pragma unroll
        for (int j = 0; j < 4; j++) acc[i][j] = 0.0f;

    for (int k = 0; k < 64; k += 4) {
        float4 qv[4], kv[4];
        #pragma unroll
        for (int i = 0; i < 4; i++) qv[i] = *(const float4*)(&Qs[ty * 4 + i][k]);
        #pragma unroll
        for (int j = 0; j < 4; j++) kv[j] = *(const float4*)(&Ks[tx * 4 + j][k]);
        #pragma unroll
        for (int i = 0; i < 4; i++)
            #pragma unroll
            for (int j = 0; j < 4; j++)
                acc[i][j] += qv[i].x * kv[j].x + qv[i].y * kv[j].y
                           + qv[i].z * kv[j].z + qv[i].w * kv[j].w;
    }

    float amMv[4], amNv[4];
    #pragma unroll
    for (int i = 0; i < 4; i++) amMv[i] = amM[ty * 4 + i];
    #pragma unroll
    for (int j = 0; j < 4; j++) amNv[j] = amN[tx * 4 + j];

    float vals[4][4];
    #pragma unroll
    for (int i = 0; i < 4; i++) {
        int m = m0 + ty * 4 + i;
        #pragma unroll
        for (int j = 0; j < 4; j++) {
            int n = n0 + tx * 4 + j;
            float msk = (1.0f - amMv[i] * amNv[j]) * NEG_BIG
                      + ((n < m) ? NEG_BIG : 0.0f);
            vals[i][j] = acc[i][j] * 0.125f - msk;
        }
    }

    for (int h = 0; h < NHEADS; h++) {
        float be[4], bo[4];
        #pragma unroll
        for (int j = 0; j < 4; j++) be[j] = bEs[h][tx * 4 + j];
        #pragma unroll
        for (int i = 0; i < 4; i++) bo[i] = bOs[h][ty * 4 + i];
        float* obase = out + ((size_t)((b * NHEADS + h) * SEQ + m0 + ty * 4)) * SEQ + n0 + tx * 4;
        #pragma unroll
        for (int i = 0; i < 4; i++) {
            float4 o4;
            o4.x = vals[i][0] + be[0] + bo[i];
            o4.y = vals[i][1] + be[1] + bo[i];
            o4.z = vals[i][2] + be[2] + bo[i];
            o4.w = vals[i][3] + be[3] + bo[i];
            *(float4*)(obase + (size_t)i * SEQ) = o4;
        }
    }
}

extern "C" void kernel_launch(void* const* d_in, const int* in_sizes, int n_in,
                              void* d_out, int out_size, void* d_ws, size_t ws_size,
                              hipStream_t stream) {
    const float* inp = (const float*)d_in[0];   // (16,512,1024)
    const float* am  = (const float*)d_in[1];   // (16,512)
    const float* W1  = (const float*)d_in[2];   // (1024,128)
    const float* b1  = (const float*)d_in[3];   // (128)
    const float* W2  = (const float*)d_in[4];   // (128,24)
    const float* b2  = (const float*)d_in[5];   // (24)
    float* out = (float*)d_out;

    // workspace: qw (2MB) | kw (2MB) | bias (768KB) | W1T bf16 (256KB)
    float* qw   = (float*)d_ws;
    float* kw   = qw + (size_t)NROWS * 64;
    float* bias = kw + (size_t)NROWS * 64;
    __bf16* w1t = (__bf16*)(bias + (size_t)NROWS * 24);

    egp_prep<<<64, 256, 0, stream>>>(W1, w1t);
    egp_stage1<<<NROWS / MTILE, 256, 0, stream>>>(inp, w1t, b1, W2, b2, qw, kw, bias);

    dim3 g2(SEQ / 64, SEQ / 64, NB);
    egp_stage2<<<g2, 256, 0, stream>>>(qw, kw, bias, am, out);
}